// Round 1
// baseline (432.620 us; speedup 1.0000x reference)
//
#include <hip/hip_runtime.h>

#define B_   512
#define C_   256
#define HWD_ 384

typedef __bf16 bf16x8 __attribute__((ext_vector_type(8)));
typedef float  f32x4  __attribute__((ext_vector_type(4)));

// ---------------- kernel 1: per-(b,c) mean over HWD=384 ----------------
// one wave per row; float2 loads (3 per lane), 64-lane xor reduce.
__global__ __launch_bounds__(256) void mean_kernel(const float* __restrict__ x,
                                                   float* __restrict__ cadj) {
    const int row  = (blockIdx.x << 2) + (threadIdx.x >> 6);
    const int lane = threadIdx.x & 63;
    const float2* p = (const float2*)(x + (size_t)row * HWD_);
    float s = 0.f;
#pragma unroll
    for (int t = 0; t < 3; ++t) {
        float2 v = p[lane + (t << 6)];
        s += v.x + v.y;
    }
#pragma unroll
    for (int off = 32; off; off >>= 1) s += __shfl_xor(s, off, 64);
    if (lane == 0) cadj[row] = s * (1.0f / HWD_);
}

// ---------------- kernel 2: out[b] = relu( ((adj .* s_b) @ fea_b) * para )
// 128x128 tile per block, K=256 in steps of 32, mfma 16x16x32 bf16.
// s_b[i,j] = 2*sigmoid(-|ca[j]-ca[i]|) computed on the fly during A staging.
__global__ __launch_bounds__(256) void gemm_kernel(const float* __restrict__ x,
                                                   const float* __restrict__ adj,
                                                   const float* __restrict__ para,
                                                   const float* __restrict__ cadj,
                                                   float* __restrict__ out) {
    const int mt = blockIdx.x;   // 0..1
    const int nt = blockIdx.y;   // 0..2
    const int b  = blockIdx.z;   // 0..511
    const int i0 = mt * 128;
    const int n0 = nt * 128;

    // rows padded to 40 bf16 (80 B stride: 16B-aligned b128 reads, 2-way bank alias = free)
    __shared__ __bf16 As[128][40];   // A[i_local][k_local]
    __shared__ __bf16 Bs[128][40];   // fea transposed: Bs[n_local][k_local]

    const int tid  = threadIdx.x;
    const int lane = tid & 63;
    const int w    = tid >> 6;
    const int wm   = w & 1, wn = w >> 1;
    const int lm   = lane & 15, quad = lane >> 4;

    const float* ca = cadj + b * C_;

    // A staging map: thread -> (row 0..127, 16-col half)
    const int a_row  = tid >> 1;
    const int a_half = tid & 1;
    const float ca_i = ca[i0 + a_row];

    // B staging map: thread -> (n 0..127, 16-row j group); transpose into Bs
    const int b_n  = tid & 127;
    const int b_jg = tid >> 7;

    f32x4 acc[4][4];
#pragma unroll
    for (int mm = 0; mm < 4; ++mm)
#pragma unroll
        for (int nn = 0; nn < 4; ++nn)
            acc[mm][nn] = (f32x4){0.f, 0.f, 0.f, 0.f};

    for (int k0 = 0; k0 < C_; k0 += 32) {
        __syncthreads();   // protect previous iteration's fragment reads
        // ---- stage A = adj .* s  (i0..i0+127) x (k0..k0+31) ----
        {
            const float* ap = adj + (size_t)(i0 + a_row) * C_ + k0 + a_half * 16;
            float4 av[4];
#pragma unroll
            for (int q = 0; q < 4; ++q) av[q] = ((const float4*)ap)[q];
            bf16x8 pk0, pk1;
#pragma unroll
            for (int jj = 0; jj < 16; ++jj) {
                float aval = ((const float*)av)[jj];
                float d = ca[k0 + a_half * 16 + jj] - ca_i;
                float t = __expf(-fabsf(d));
                float s = 2.f * t / (1.f + t);
                float v = aval * s;
                if (jj < 8) pk0[jj & 7] = (__bf16)v;
                else        pk1[jj & 7] = (__bf16)v;
            }
            *(bf16x8*)&As[a_row][a_half * 16]     = pk0;
            *(bf16x8*)&As[a_row][a_half * 16 + 8] = pk1;
        }
        // ---- stage Bt: fea[j][n] -> Bs[n][j] (transpose at staging) ----
        {
            const float* xp = x + (size_t)(b * C_ + k0 + b_jg * 16) * HWD_ + n0 + b_n;
            bf16x8 pk0, pk1;
#pragma unroll
            for (int jj = 0; jj < 16; ++jj) {
                float v = xp[(size_t)jj * HWD_];   // coalesced across lanes (n contiguous)
                if (jj < 8) pk0[jj & 7] = (__bf16)v;
                else        pk1[jj & 7] = (__bf16)v;
            }
            *(bf16x8*)&Bs[b_n][b_jg * 16]     = pk0;
            *(bf16x8*)&Bs[b_n][b_jg * 16 + 8] = pk1;
        }
        __syncthreads();
        // ---- fragment loads (single b128 each) + 16 mfma ----
        bf16x8 af[4], bfr[4];
#pragma unroll
        for (int mm = 0; mm < 4; ++mm)
            af[mm] = *(const bf16x8*)&As[wm * 64 + mm * 16 + lm][quad * 8];
#pragma unroll
        for (int nn = 0; nn < 4; ++nn)
            bfr[nn] = *(const bf16x8*)&Bs[wn * 64 + nn * 16 + lm][quad * 8];
#pragma unroll
        for (int mm = 0; mm < 4; ++mm)
#pragma unroll
            for (int nn = 0; nn < 4; ++nn)
                acc[mm][nn] = __builtin_amdgcn_mfma_f32_16x16x32_bf16(
                    af[mm], bfr[nn], acc[mm][nn], 0, 0, 0);
    }

    // ---- epilogue: *para, relu, store ----
#pragma unroll
    for (int mm = 0; mm < 4; ++mm) {
#pragma unroll
        for (int r = 0; r < 4; ++r) {
            const int i = i0 + wm * 64 + mm * 16 + quad * 4 + r;
            const float* pp = para + (size_t)i * HWD_;
            float* op = out + ((size_t)b * C_ + i) * HWD_;
#pragma unroll
            for (int nn = 0; nn < 4; ++nn) {
                const int n = n0 + wn * 64 + nn * 16 + lm;
                float v = acc[mm][nn][r] * pp[n];
                op[n] = v > 0.f ? v : 0.f;
            }
        }
    }
}

extern "C" void kernel_launch(void* const* d_in, const int* in_sizes, int n_in,
                              void* d_out, int out_size, void* d_ws, size_t ws_size,
                              hipStream_t stream) {
    const float* x    = (const float*)d_in[0];
    const float* adj  = (const float*)d_in[1];
    const float* para = (const float*)d_in[2];
    float* out  = (float*)d_out;
    float* cadj = (float*)d_ws;   // 512*256 floats = 512 KB

    mean_kernel<<<dim3((B_ * C_) / 4), 256, 0, stream>>>(x, cadj);
    gemm_kernel<<<dim3(2, 3, B_), 256, 0, stream>>>(x, adj, para, cadj, out);
}